// Round 1
// baseline (521.368 us; speedup 1.0000x reference)
//
#include <hip/hip_runtime.h>
#include <stdint.h>

typedef _Float16 f16;
typedef _Float16 f16x4 __attribute__((ext_vector_type(4)));
typedef _Float16 f16x8 __attribute__((ext_vector_type(8)));
typedef float f32x4 __attribute__((ext_vector_type(4)));

#define D_DIM 256
#define K_CB 4096
#define N_ROWS 65536
#define BM 128
#define BN 128
#define N_TILES 32
#define ZQ_SIZE 16777216
#define LOSS_OFF 16777216
#define IDS_OFF 16777217

// workspace layout (bytes)
#define WS_CHI 0
#define WS_CLO 2097152
#define WS_CN  4194304
#define WS_ZN  4210688

// direct-to-LDS 16B async copy (per-lane global addr, wave-uniform LDS base + lane*16)
#define GL_LDS(g, s_) __builtin_amdgcn_global_load_lds( \
    (const __attribute__((address_space(1))) void*)(g), \
    (__attribute__((address_space(3))) void*)(s_), 16, 0, 0)

// ---------------- K0: codebook prep: f16 split (hi, lo*2048) + row norms + zero loss slot ----
__global__ __launch_bounds__(256) void k_prep_cb(const float* __restrict__ cb,
                                                 f16* __restrict__ chi,
                                                 f16* __restrict__ clo,
                                                 float* __restrict__ cn,
                                                 float* __restrict__ loss_slot) {
    const int tid = threadIdx.x;
    const int w = tid >> 6, l = tid & 63;
    const int row = blockIdx.x * 4 + w;            // one wave per codebook row
    const float4 v = ((const float4*)(cb))[row * 64 + l];
    float a[4] = {v.x, v.y, v.z, v.w};
    f16x4 h4, l4;
    float ss = 0.0f;
#pragma unroll
    for (int i = 0; i < 4; ++i) {
        float x = a[i];
        f16 h = (f16)x;
        h4[i] = h;
        l4[i] = (f16)((x - (float)h) * 2048.0f);   // residual, scaled out of denormal range
        ss += x * x;
    }
#pragma unroll
    for (int m = 32; m >= 1; m >>= 1) ss += __shfl_xor(ss, m);
    ((f16x4*)(chi))[row * 64 + l] = h4;
    ((f16x4*)(clo))[row * 64 + l] = l4;
    if (l == 0) cn[row] = ss;
    if (blockIdx.x == 0 && tid == 0) *loss_slot = 0.0f;
}

// ---------------- K0b: z row norms (fp32, mirrors reference sum(z*z, axis=1)) ----
__global__ __launch_bounds__(256) void k_prep_zn(const float* __restrict__ z,
                                                 float* __restrict__ zn) {
    const int tid = threadIdx.x;
    const int w = tid >> 6, l = tid & 63;
    const int rb = blockIdx.x * BM;
#pragma unroll 4
    for (int p = 0; p < 32; ++p) {
        const int row = rb + p * 4 + w;
        const float4 v = ((const float4*)(z))[row * 64 + l];
        float ss = v.x * v.x + v.y * v.y + v.z * v.z + v.w * v.w;
#pragma unroll
        for (int m = 32; m >= 1; m >>= 1) ss += __shfl_xor(ss, m);
        if (l == 0) zn[row] = ss;
    }
}

// ---------------- K1: distance GEMM (f16-split MFMA) + argmin + gather + loss ----
// LDS (163840 B dynamic):
//   [0,65536)       A_hi : 128 rows x 256 f16, 16B blocks XOR-swizzled by (row&7)
//   [65536,131072)  A_lo
//   [131072,147456) B buf0 : hi 8192 | lo 8192, entry-major, blocks swizzled by ((e>>1)&3)
//   [147456,163840) B buf1
//   B region reused after main loop for merge arrays + loss scratch.
__global__ __launch_bounds__(256, 1) void k_main(const float* __restrict__ z,
                                                 const float* __restrict__ cb,
                                                 const f16* __restrict__ chi,
                                                 const f16* __restrict__ clo,
                                                 const float* __restrict__ cn,
                                                 const float* __restrict__ znws,
                                                 float* __restrict__ out) {
    extern __shared__ char smem[];
    const int tid = threadIdx.x;
    const int w = tid >> 6, l = tid & 63;
    const int wm = w >> 1, wn = w & 1;             // 2x2 wave grid, 64x64 tiles
    const int l15 = l & 15, qh = l >> 4;
    const int blk = blockIdx.x;
    const float* ztile = z + (size_t)blk * (BM * D_DIM);

    // ---- stage A once: fp32 -> (hi, lo*2048) f16, swizzled ----
#pragma unroll 4
    for (int p = 0; p < 32; ++p) {
        const int r = p * 4 + w;                   // wave covers one full row per pass
        const float4 v = ((const float4*)ztile)[r * 64 + l];
        float a[4] = {v.x, v.y, v.z, v.w};
        f16x4 h4, l4;
#pragma unroll
        for (int i = 0; i < 4; ++i) {
            f16 h = (f16)a[i];
            h4[i] = h;
            l4[i] = (f16)((a[i] - (float)h) * 2048.0f);
        }
        const int addr = r * 512 + ((((l >> 1) ^ (r & 7))) << 4) + ((l & 1) << 3);
        *(f16x4*)(smem + addr) = h4;
        *(f16x4*)(smem + 65536 + addr) = l4;
    }

    // ---- per-lane z row-norms for this lane's 16 C-layout row slots ----
    float znr[16];
#pragma unroll
    for (int s = 0; s < 16; ++s) {
        const int row = wm * 64 + (s >> 2) * 16 + qh * 4 + (s & 3);
        znr[s] = znws[blk * BM + row];
    }

    // ---- codebook-norm prefetch (tile 0) ----
    float cnNext[4];
#pragma unroll
    for (int j = 0; j < 4; ++j) cnNext[j] = cn[wn * 64 + j * 16 + l15];

    // ---- B staging constants: lane tid fills LDS block tid (and tid+256) ----
    const int e0 = tid >> 2;
    const int q0 = (tid & 3) ^ ((e0 >> 1) & 3);    // logical k-block for this phys slot
    const int offE = e0 * 256 + q0 * 8;            // f16 elements into codebook row

    // ---- fragment read address constants ----
    int rowb[4], rs[4], bcon[4];
#pragma unroll
    for (int i = 0; i < 4; ++i) {
        const int r = wm * 64 + i * 16 + l15;
        rowb[i] = r * 512;
        rs[i] = r & 7;
    }
#pragma unroll
    for (int j = 0; j < 4; ++j) {
        const int e = wn * 64 + j * 16 + l15;
        bcon[j] = e * 64 + ((qh ^ ((e >> 1) & 3)) << 4);
    }

    // prologue: issue B loads for step 0 into buf0
    {
        const f16* gh = chi + offE;
        const f16* gl = clo + offE;
        char* bb = smem + 131072 + w * 1024;
        GL_LDS(gh, bb);            GL_LDS(gh + 16384, bb + 4096);
        GL_LDS(gl, bb + 8192);     GL_LDS(gl + 16384, bb + 12288);
    }

    f32x4 accA[4][4], accB[4][4];
    float rmin[16];
    uint32_t ridx[16];
#pragma unroll
    for (int s = 0; s < 16; ++s) { rmin[s] = 3.0e38f; ridx[s] = 0u; }
    float cnCur[4];

    for (int tile = 0; tile < N_TILES; ++tile) {
#pragma unroll
        for (int j = 0; j < 4; ++j) cnCur[j] = cnNext[j];
#pragma unroll
        for (int i = 0; i < 4; ++i)
#pragma unroll
            for (int j = 0; j < 4; ++j) {
                accA[i][j] = (f32x4){0.f, 0.f, 0.f, 0.f};
                accB[i][j] = (f32x4){0.f, 0.f, 0.f, 0.f};
            }
#pragma unroll
        for (int kc = 0; kc < 8; ++kc) {
            __syncthreads();                        // B[step] landed; prev buf reads done
            const int step = tile * 8 + kc;
            if (step + 1 < 256) {                   // prefetch next chunk into other buffer
                const int nt = (step + 1) >> 3, nk = (step + 1) & 7;
                const int goff = nt * (BN * D_DIM) + nk * 32 + offE;
                char* bb = smem + 131072 + ((step + 1) & 1) * 16384 + w * 1024;
                const f16* gh = chi + goff;
                const f16* gl = clo + goff;
                GL_LDS(gh, bb);        GL_LDS(gh + 16384, bb + 4096);
                GL_LDS(gl, bb + 8192); GL_LDS(gl + 16384, bb + 12288);
            }
            if (kc == 0) {                          // prefetch next tile's cnorms
                const int tn = (tile + 1 < N_TILES) ? tile + 1 : tile;
#pragma unroll
                for (int j = 0; j < 4; ++j)
                    cnNext[j] = cn[tn * BN + wn * 64 + j * 16 + l15];
            }
            const char* bbase = smem + 131072 + (step & 1) * 16384;
            f16x8 ah[4], al[4], bh[4], bl[4];
#pragma unroll
            for (int i = 0; i < 4; ++i) {
                const int t = ((kc << 2) + qh) ^ rs[i];
                const int a = rowb[i] + (t << 4);
                ah[i] = *(const f16x8*)(smem + a);
                al[i] = *(const f16x8*)(smem + 65536 + a);
            }
#pragma unroll
            for (int j = 0; j < 4; ++j) {
                bh[j] = *(const f16x8*)(bbase + bcon[j]);
                bl[j] = *(const f16x8*)(bbase + 8192 + bcon[j]);
            }
#pragma unroll
            for (int i = 0; i < 4; ++i)
#pragma unroll
                for (int j = 0; j < 4; ++j) {
                    accA[i][j] = __builtin_amdgcn_mfma_f32_16x16x32_f16(ah[i], bh[j], accA[i][j], 0, 0, 0);
                    accB[i][j] = __builtin_amdgcn_mfma_f32_16x16x32_f16(al[i], bh[j], accB[i][j], 0, 0, 0);
                    accB[i][j] = __builtin_amdgcn_mfma_f32_16x16x32_f16(ah[i], bl[j], accB[i][j], 0, 0, 0);
                }
        }
        // epilogue: d2 = (||z||^2 - 2*M) + ||c||^2, running argmin (cols ascend -> strict <)
        const int colb = tile * BN + wn * 64 + l15;
#pragma unroll
        for (int j = 0; j < 4; ++j) {
            const uint32_t col = colb + j * 16;
            const float cnj = cnCur[j];
#pragma unroll
            for (int i = 0; i < 4; ++i)
#pragma unroll
                for (int rr = 0; rr < 4; ++rr) {
                    const int s = i * 4 + rr;
                    const float M = accA[i][j][rr] + accB[i][j][rr] * (1.0f / 2048.0f);
                    const float d2 = (znr[s] - 2.0f * M) + cnj;
                    if (d2 < rmin[s]) { rmin[s] = d2; ridx[s] = col; }
                }
        }
    }

    // ---- argmin reduce across the 16 lanes sharing each row (idx tie-break: smaller) ----
#pragma unroll
    for (int s = 0; s < 16; ++s) {
        float v = rmin[s];
        uint32_t ix = ridx[s];
#pragma unroll
        for (int m = 1; m <= 8; m <<= 1) {
            const float ov = __shfl_xor(v, m);
            const uint32_t oi = __shfl_xor(ix, m);
            if (ov < v || (ov == v && oi < ix)) { v = ov; ix = oi; }
        }
        rmin[s] = v; ridx[s] = ix;
    }
    __syncthreads();                               // B region now reusable
    float* mVal = (float*)(smem + 131072);
    uint32_t* mIdx = (uint32_t*)(smem + 131072 + 512);
    float* lossW = (float*)(smem + 131072 + 1024);
    if (wn == 0 && l15 == 0) {
#pragma unroll
        for (int s = 0; s < 16; ++s) {
            const int row = wm * 64 + (s >> 2) * 16 + qh * 4 + (s & 3);
            mVal[row] = rmin[s];
            mIdx[row] = ridx[s];
        }
    }
    __syncthreads();
    if (wn == 1 && l15 == 0) {                     // merge the two column-half waves
#pragma unroll
        for (int s = 0; s < 16; ++s) {
            const int row = wm * 64 + (s >> 2) * 16 + qh * 4 + (s & 3);
            const float v = rmin[s];
            const uint32_t ix = ridx[s];
            if (v < mVal[row] || (v == mVal[row] && ix < mIdx[row])) {
                mVal[row] = v; mIdx[row] = ix;
            }
        }
    }
    __syncthreads();
    if (tid < BM) out[IDS_OFF + blk * BM + tid] = (float)mIdx[tid];

    // ---- fused gather z_q + commitment loss ----
    float lacc = 0.0f;
    for (int it = 0; it < 32; ++it) {
        const int row = it * 4 + w;                // wave covers one full row per iter
        const int col = (int)mIdx[row];
        const float4 c4 = ((const float4*)cb)[col * 64 + l];
        const float4 z4 = ((const float4*)ztile)[row * 64 + l];
        ((float4*)out)[(blk * BM + row) * 64 + l] = c4;
        const float dx = c4.x - z4.x, dy = c4.y - z4.y;
        const float dzv = c4.z - z4.z, dwv = c4.w - z4.w;
        lacc += dx * dx + dy * dy + dzv * dzv + dwv * dwv;
    }
#pragma unroll
    for (int m = 32; m >= 1; m >>= 1) lacc += __shfl_xor(lacc, m);
    if (l == 0) lossW[w] = lacc;
    __syncthreads();
    if (tid == 0) {
        const float tot = (lossW[0] + lossW[1] + lossW[2] + lossW[3]) * (1.25f / 16777216.0f);
        atomicAdd(out + LOSS_OFF, tot);
    }
}

extern "C" void kernel_launch(void* const* d_in, const int* in_sizes, int n_in,
                              void* d_out, int out_size, void* d_ws, size_t ws_size,
                              hipStream_t stream) {
    (void)in_sizes; (void)n_in; (void)out_size; (void)ws_size;
    const float* z = (const float*)d_in[0];
    const float* cb = (const float*)d_in[1];
    float* out = (float*)d_out;
    char* ws = (char*)d_ws;
    f16* chi = (f16*)(ws + WS_CHI);
    f16* clo = (f16*)(ws + WS_CLO);
    float* cn = (float*)(ws + WS_CN);
    float* zn = (float*)(ws + WS_ZN);

    // opt in to 160 KiB dynamic LDS (idempotent; not a stream op, capture-safe)
    hipFuncSetAttribute((const void*)k_main,
                        hipFuncAttributeMaxDynamicSharedMemorySize, 163840);

    k_prep_cb<<<K_CB / 4, 256, 0, stream>>>(cb, chi, clo, cn, out + LOSS_OFF);
    k_prep_zn<<<N_ROWS / BM, 256, 0, stream>>>(z, zn);
    k_main<<<N_ROWS / BM, 256, 163840, stream>>>(z, cb, chi, clo, cn, zn, out);
}